// Round 7
// baseline (139.525 us; speedup 1.0000x reference)
//
#include <hip/hip_runtime.h>

// YOLO loss: pred/target (N,14,14,30) fp32 -> scalar.
// S=14, B=2, C=20, cell stride = 30 floats = 120 bytes.
//
// R7 = R6 (two-phase 31 KB async-DMA LDS staging, fully inlined) + fused
// final reduction via last-block-arrival. R3's fused version regressed from
// helper-function scratch spill (188 MB WRITE_SIZE), NOT from the atomics
// (R4 removed atomics, still slow; R5 inlined, fast). Protocol: plain
// partial stores ordered by ACQ_REL agent-scope counter RMW; last block
// does a fixed-order double sum -> deterministic.

#define S_DIM 14
#define CELLF 30
#define TPB 256
#define CHUNKF (TPB * CELLF)   // 7680 floats per array per block
#define CHUNK4 (CHUNKF / 4)    // 1920 float4 per array per block

constexpr float LAMBDA_COORD = 5.0f;
constexpr float LAMBDA_NOOBJ = 0.5f;
constexpr float EPSF = 1e-7f;

__device__ __forceinline__ void gl2lds16(const float4* g, float4* l) {
    __builtin_amdgcn_global_load_lds(
        (const __attribute__((address_space(1))) void*)g,
        (__attribute__((address_space(3))) void*)l,
        16 /*bytes, literal*/, 0 /*offset*/, 0 /*aux*/);
}

__device__ __forceinline__ float iou_xywh(float cx1, float cy1, float w1, float h1,
                                          float cx2, float cy2, float w2, float h2) {
    float ix1 = fmaxf(cx1 - 0.5f * w1, cx2 - 0.5f * w2);
    float iy1 = fmaxf(cy1 - 0.5f * h1, cy2 - 0.5f * h2);
    float ix2 = fminf(cx1 + 0.5f * w1, cx2 + 0.5f * w2);
    float iy2 = fminf(cy1 + 0.5f * h1, cy2 + 0.5f * h2);
    float inter = fmaxf(ix2 - ix1, 0.0f) * fmaxf(iy2 - iy1, 0.0f);
    float uni = w1 * h1 + w2 * h2 - inter + EPSF;
    return inter / uni;
}

__global__ __launch_bounds__(TPB) void yolo_loss_kernel(
        const float* __restrict__ pred,
        const float* __restrict__ tgt,
        float* __restrict__ partial,
        unsigned* __restrict__ counter,
        float* __restrict__ out,
        int nblocks, float inv_n) {
    __shared__ float lds[CHUNKF];   // 30720 B

    const int tid = threadIdx.x;
    const size_t base4 = (size_t)blockIdx.x * CHUNK4;
    const float4* pred4 = reinterpret_cast<const float4*>(pred);
    const float4* tgt4  = reinterpret_cast<const float4*>(tgt);
    float4* lds4 = reinterpret_cast<float4*>(lds);
    const float2* lds2 = reinterpret_cast<const float2*>(lds);

    // ---------------- phase 1: pred --DMA--> LDS -> p[30] ----------------
    #pragma unroll
    for (int k = 0; k < 8; ++k) {
        int i = tid + k * TPB;                   // guard at 1920 is wave-uniform
        if (i < CHUNK4) gl2lds16(pred4 + base4 + i, lds4 + i);
    }
    __syncthreads();

    float p[CELLF];
    #pragma unroll
    for (int k = 0; k < 15; ++k) {
        float2 v = lds2[tid * 15 + k];
        p[2 * k] = v.x; p[2 * k + 1] = v.y;
    }
    __syncthreads();

    // ---------------- phase 2: tgt --DMA--> LDS -> t[30] ----------------
    #pragma unroll
    for (int k = 0; k < 8; ++k) {
        int i = tid + k * TPB;
        if (i < CHUNK4) gl2lds16(tgt4 + base4 + i, lds4 + i);
    }
    __syncthreads();

    float t[CELLF];
    #pragma unroll
    for (int k = 0; k < 15; ++k) {
        float2 v = lds2[tid * 15 + k];
        t[2 * k] = v.x; t[2 * k + 1] = v.y;
    }

    // ---------------- per-cell loss ----------------
    // layout per cell: [0..4]=box0 cx,cy,w,h,conf  [5..9]=box1  [10..29]=classes
    float iou00 = iou_xywh(p[0], p[1], p[2], p[3], t[0], t[1], t[2], t[3]);
    float iou10 = iou_xywh(p[5], p[6], p[7], p[8], t[0], t[1], t[2], t[3]);
    float iou11 = iou_xywh(p[5], p[6], p[7], p[8], t[5], t[6], t[7], t[8]);

    bool obj = t[4] > 0.0f;          // tgt conf of box0 (== obj mask)
    bool best1 = iou10 > iou00;      // argmax first-max tie-break

    float d0 = p[4] - t[4];  float c0 = d0 * d0;
    float d1 = p[9] - t[9];  float c1 = d1 * d1;
    float conf_best  = best1 ? c1 : c0;
    float conf_other = best1 ? c0 : c1;

    float iou_pair_best = best1 ? iou11 : iou00;
    float coord = 1.0f - sqrtf(fmaxf(iou_pair_best, EPSF));  // ALPHA=0.5

    float cls = 0.0f;
    #pragma unroll
    for (int k = 0; k < 20; ++k) {
        float d = p[10 + k] - t[10 + k];
        cls = fmaf(d, d, cls);
    }

    float loss_obj   = obj ? conf_best : 0.0f;
    float loss_noobj = obj ? conf_other : (c0 + c1);
    float loss_coord = obj ? coord : 0.0f;
    float loss_cls   = obj ? cls : 0.0f;

    float loss = LAMBDA_COORD * loss_coord + loss_obj
               + LAMBDA_NOOBJ * loss_noobj + loss_cls;

    // ---------------- block reduce ----------------
    #pragma unroll
    for (int off = 32; off > 0; off >>= 1)
        loss += __shfl_down(loss, off, 64);

    __shared__ float wsum[4];
    __shared__ int amLast;
    int lane = tid & 63;
    int wid  = tid >> 6;
    if (lane == 0) wsum[wid] = loss;
    __syncthreads();

    if (tid == 0) {
        partial[blockIdx.x] = wsum[0] + wsum[1] + wsum[2] + wsum[3];
        // ACQ_REL RMW: release orders/flushes the partial store (agent scope),
        // acquire side (when we are last) makes all partials visible.
        unsigned prev = __hip_atomic_fetch_add(counter, 1u,
                           __ATOMIC_ACQ_REL, __HIP_MEMORY_SCOPE_AGENT);
        amLast = (prev == (unsigned)(nblocks - 1));
    }
    __syncthreads();

    // ---------------- last block: fixed-order final reduce ----------------
    if (amLast) {
        double s = 0.0;
        for (int i = tid; i < nblocks; i += TPB)
            s += (double)partial[i];
        #pragma unroll
        for (int off = 32; off > 0; off >>= 1)
            s += __shfl_down(s, off, 64);
        __shared__ double dsum[4];
        if (lane == 0) dsum[wid] = s;
        __syncthreads();
        if (tid == 0)
            out[0] = (float)((dsum[0] + dsum[1] + dsum[2] + dsum[3]) * (double)inv_n);
    }
}

extern "C" void kernel_launch(void* const* d_in, const int* in_sizes, int n_in,
                              void* d_out, int out_size, void* d_ws, size_t ws_size,
                              hipStream_t stream) {
    const float* pred = (const float*)d_in[0];
    const float* tgt  = (const float*)d_in[1];
    float* out = (float*)d_out;

    int total_elems = in_sizes[0];          // N * S * S * 30
    int ncells = total_elems / CELLF;       // N * 196 = 802816 (exact 3136*256)
    int N = ncells / (S_DIM * S_DIM);       // 4096

    int nblocks = ncells / TPB;             // 3136
    float* partial = (float*)d_ws;          // nblocks * 4 B
    unsigned* counter = (unsigned*)((char*)d_ws + 16384);

    hipMemsetAsync(counter, 0, sizeof(unsigned), stream);
    yolo_loss_kernel<<<nblocks, TPB, 0, stream>>>(
        pred, tgt, partial, counter, out, nblocks, 1.0f / (float)N);
}

// Round 8
// 93.353 us; speedup vs baseline: 1.4946x; 1.4946x over previous
//
#include <hip/hip_runtime.h>

// YOLO loss: pred/target (N,14,14,30) fp32 -> scalar.
// S=14, B=2, C=20, cell stride = 30 floats = 120 bytes.
//
// R8 = R6 staging (two-phase 31 KB async-DMA LDS, fully inlined) + fused
// FENCE-FREE reduction:
//   - per-block partial -> 64-bit fixed point (x 2^24), relaxed agent-scope
//     integer fetch_add (exactly associative -> bit-deterministic, no
//     acq/rel -> no buffer_wbl2/buffer_inv L2 nukes; R7 post-mortem: one
//     ACQ_REL RMW per block tripled kernel time by invalidating L2).
//   - relaxed counter RMW (ordered after acc-add by consuming its return)
//     elects last block, which reads acc and writes out[0].
// ws: [0..8) acc u64, [8..12) counter u32 — re-zeroed via hipMemsetAsync.

#define S_DIM 14
#define CELLF 30
#define TPB 256
#define CHUNKF (TPB * CELLF)   // 7680 floats per array per block
#define CHUNK4 (CHUNKF / 4)    // 1920 float4 per array per block

constexpr float LAMBDA_COORD = 5.0f;
constexpr float LAMBDA_NOOBJ = 0.5f;
constexpr float EPSF = 1e-7f;
constexpr double FXSCALE = 16777216.0;   // 2^24

__device__ __forceinline__ void gl2lds16(const float4* g, float4* l) {
    __builtin_amdgcn_global_load_lds(
        (const __attribute__((address_space(1))) void*)g,
        (__attribute__((address_space(3))) void*)l,
        16 /*bytes, literal*/, 0 /*offset*/, 0 /*aux*/);
}

__device__ __forceinline__ float iou_xywh(float cx1, float cy1, float w1, float h1,
                                          float cx2, float cy2, float w2, float h2) {
    float ix1 = fmaxf(cx1 - 0.5f * w1, cx2 - 0.5f * w2);
    float iy1 = fmaxf(cy1 - 0.5f * h1, cy2 - 0.5f * h2);
    float ix2 = fminf(cx1 + 0.5f * w1, cx2 + 0.5f * w2);
    float iy2 = fminf(cy1 + 0.5f * h1, cy2 + 0.5f * h2);
    float inter = fmaxf(ix2 - ix1, 0.0f) * fmaxf(iy2 - iy1, 0.0f);
    float uni = w1 * h1 + w2 * h2 - inter + EPSF;
    return inter / uni;
}

__global__ __launch_bounds__(TPB) void yolo_loss_kernel(
        const float* __restrict__ pred,
        const float* __restrict__ tgt,
        unsigned long long* __restrict__ acc,
        unsigned* __restrict__ counter,
        float* __restrict__ out,
        int nblocks, float inv_n) {
    __shared__ float lds[CHUNKF];   // 30720 B

    const int tid = threadIdx.x;
    const size_t base4 = (size_t)blockIdx.x * CHUNK4;
    const float4* pred4 = reinterpret_cast<const float4*>(pred);
    const float4* tgt4  = reinterpret_cast<const float4*>(tgt);
    float4* lds4 = reinterpret_cast<float4*>(lds);
    const float2* lds2 = reinterpret_cast<const float2*>(lds);

    // ---------------- phase 1: pred --DMA--> LDS -> p[30] ----------------
    #pragma unroll
    for (int k = 0; k < 8; ++k) {
        int i = tid + k * TPB;                   // guard at 1920 is wave-uniform
        if (i < CHUNK4) gl2lds16(pred4 + base4 + i, lds4 + i);
    }
    __syncthreads();

    float p[CELLF];
    #pragma unroll
    for (int k = 0; k < 15; ++k) {
        float2 v = lds2[tid * 15 + k];
        p[2 * k] = v.x; p[2 * k + 1] = v.y;
    }
    __syncthreads();

    // ---------------- phase 2: tgt --DMA--> LDS -> t[30] ----------------
    #pragma unroll
    for (int k = 0; k < 8; ++k) {
        int i = tid + k * TPB;
        if (i < CHUNK4) gl2lds16(tgt4 + base4 + i, lds4 + i);
    }
    __syncthreads();

    float t[CELLF];
    #pragma unroll
    for (int k = 0; k < 15; ++k) {
        float2 v = lds2[tid * 15 + k];
        t[2 * k] = v.x; t[2 * k + 1] = v.y;
    }

    // ---------------- per-cell loss ----------------
    // layout per cell: [0..4]=box0 cx,cy,w,h,conf  [5..9]=box1  [10..29]=classes
    float iou00 = iou_xywh(p[0], p[1], p[2], p[3], t[0], t[1], t[2], t[3]);
    float iou10 = iou_xywh(p[5], p[6], p[7], p[8], t[0], t[1], t[2], t[3]);
    float iou11 = iou_xywh(p[5], p[6], p[7], p[8], t[5], t[6], t[7], t[8]);

    bool obj = t[4] > 0.0f;          // tgt conf of box0 (== obj mask)
    bool best1 = iou10 > iou00;      // argmax first-max tie-break

    float d0 = p[4] - t[4];  float c0 = d0 * d0;
    float d1 = p[9] - t[9];  float c1 = d1 * d1;
    float conf_best  = best1 ? c1 : c0;
    float conf_other = best1 ? c0 : c1;

    float iou_pair_best = best1 ? iou11 : iou00;
    float coord = 1.0f - sqrtf(fmaxf(iou_pair_best, EPSF));  // ALPHA=0.5

    float cls = 0.0f;
    #pragma unroll
    for (int k = 0; k < 20; ++k) {
        float d = p[10 + k] - t[10 + k];
        cls = fmaf(d, d, cls);
    }

    float loss_obj   = obj ? conf_best : 0.0f;
    float loss_noobj = obj ? conf_other : (c0 + c1);
    float loss_coord = obj ? coord : 0.0f;
    float loss_cls   = obj ? cls : 0.0f;

    float loss = LAMBDA_COORD * loss_coord + loss_obj
               + LAMBDA_NOOBJ * loss_noobj + loss_cls;

    // ---------------- block reduce ----------------
    #pragma unroll
    for (int off = 32; off > 0; off >>= 1)
        loss += __shfl_down(loss, off, 64);

    __shared__ float wsum[4];
    __shared__ int amLast;
    int lane = tid & 63;
    int wid  = tid >> 6;
    if (lane == 0) wsum[wid] = loss;
    __syncthreads();

    if (tid == 0) {
        // exact fixed-point block contribution (order-independent total)
        double bsum = (double)wsum[0] + wsum[1] + wsum[2] + wsum[3];
        unsigned long long fx = (unsigned long long)(long long)llrint(bsum * FXSCALE);
        unsigned long long old = __hip_atomic_fetch_add(acc, fx,
                                   __ATOMIC_RELAXED, __HIP_MEMORY_SCOPE_AGENT);
        // consume 'old' so the wave waits for the acc RMW to complete
        // before issuing the counter RMW (orders the two atomics).
        asm volatile("" : "+v"(old));
        unsigned prev = __hip_atomic_fetch_add(counter, 1u,
                                   __ATOMIC_RELAXED, __HIP_MEMORY_SCOPE_AGENT);
        amLast = (prev == (unsigned)(nblocks - 1));
        if (amLast) {
            unsigned long long tot = __hip_atomic_load(acc,
                                   __ATOMIC_RELAXED, __HIP_MEMORY_SCOPE_AGENT);
            out[0] = (float)(((double)(long long)tot / FXSCALE) * (double)inv_n);
        }
    }
}

extern "C" void kernel_launch(void* const* d_in, const int* in_sizes, int n_in,
                              void* d_out, int out_size, void* d_ws, size_t ws_size,
                              hipStream_t stream) {
    const float* pred = (const float*)d_in[0];
    const float* tgt  = (const float*)d_in[1];
    float* out = (float*)d_out;

    int total_elems = in_sizes[0];          // N * S * S * 30
    int ncells = total_elems / CELLF;       // N * 196 = 802816 (exact 3136*256)
    int N = ncells / (S_DIM * S_DIM);       // 4096

    int nblocks = ncells / TPB;             // 3136
    unsigned long long* acc = (unsigned long long*)d_ws;
    unsigned* counter = (unsigned*)((char*)d_ws + 8);

    hipMemsetAsync(d_ws, 0, 16, stream);    // zero acc + counter every call
    yolo_loss_kernel<<<nblocks, TPB, 0, stream>>>(
        pred, tgt, acc, counter, out, nblocks, 1.0f / (float)N);
}

// Round 9
// 45.011 us; speedup vs baseline: 3.0998x; 2.0740x over previous
//
#include <hip/hip_runtime.h>

// YOLO loss: pred/target (N,14,14,30) fp32 -> scalar.
// S=14, B=2, C=20, cell stride = 30 floats = 120 bytes.
//
// R9: single-phase async-DMA staging — both arrays' 16 global_load_lds
// issued back-to-back into one 61440 B LDS block (pred then tgt), ONE
// barrier drain instead of three. Two-kernel reduce (fusion abandoned:
// R3/R4 scratch spill, R7 ACQ_REL L2-invalidate, R8 same-cacheline RMW
// ping-pong — every cross-block protocol cost more than the ~5 us tail).

#define S_DIM 14
#define CELLF 30
#define TPB 256
#define CHUNKF (TPB * CELLF)   // 7680 floats per array per block
#define CHUNK4 (CHUNKF / 4)    // 1920 float4 per array per block

constexpr float LAMBDA_COORD = 5.0f;
constexpr float LAMBDA_NOOBJ = 0.5f;
constexpr float EPSF = 1e-7f;

__device__ __forceinline__ void gl2lds16(const float4* g, float4* l) {
    __builtin_amdgcn_global_load_lds(
        (const __attribute__((address_space(1))) void*)g,
        (__attribute__((address_space(3))) void*)l,
        16 /*bytes, literal*/, 0 /*offset*/, 0 /*aux*/);
}

__device__ __forceinline__ float iou_xywh(float cx1, float cy1, float w1, float h1,
                                          float cx2, float cy2, float w2, float h2) {
    float ix1 = fmaxf(cx1 - 0.5f * w1, cx2 - 0.5f * w2);
    float iy1 = fmaxf(cy1 - 0.5f * h1, cy2 - 0.5f * h2);
    float ix2 = fminf(cx1 + 0.5f * w1, cx2 + 0.5f * w2);
    float iy2 = fminf(cy1 + 0.5f * h1, cy2 + 0.5f * h2);
    float inter = fmaxf(ix2 - ix1, 0.0f) * fmaxf(iy2 - iy1, 0.0f);
    float uni = w1 * h1 + w2 * h2 - inter + EPSF;
    return inter / uni;
}

__global__ __launch_bounds__(TPB) void yolo_loss_kernel(
        const float* __restrict__ pred,
        const float* __restrict__ tgt,
        float* __restrict__ partial) {
    __shared__ float lds[2 * CHUNKF];   // 61440 B: [0:7680)=pred, [7680:15360)=tgt

    const int tid = threadIdx.x;
    const size_t base4 = (size_t)blockIdx.x * CHUNK4;
    const float4* pred4 = reinterpret_cast<const float4*>(pred);
    const float4* tgt4  = reinterpret_cast<const float4*>(tgt);
    float4* lds4 = reinterpret_cast<float4*>(lds);
    const float2* lds2 = reinterpret_cast<const float2*>(lds);

    // ---- stage both arrays: 16 async DMAs in flight, one drain ----
    #pragma unroll
    for (int k = 0; k < 8; ++k) {
        int i = tid + k * TPB;                    // guard splits at 1920 = 30 waves: uniform
        if (i < CHUNK4) gl2lds16(pred4 + base4 + i, lds4 + i);
    }
    #pragma unroll
    for (int k = 0; k < 8; ++k) {
        int i = tid + k * TPB;
        if (i < CHUNK4) gl2lds16(tgt4 + base4 + i, lds4 + CHUNK4 + i);
    }
    __syncthreads();                              // single vmcnt drain

    // ---- per-cell gather ----
    float p[CELLF], t[CELLF];
    #pragma unroll
    for (int k = 0; k < 15; ++k) {
        float2 v = lds2[tid * 15 + k];            // ~4-way bank, ok
        p[2 * k] = v.x; p[2 * k + 1] = v.y;
    }
    #pragma unroll
    for (int k = 0; k < 15; ++k) {
        float2 v = lds2[2 * CHUNK4 + tid * 15 + k];   // tgt region (float2 idx 3840+)
        t[2 * k] = v.x; t[2 * k + 1] = v.y;
    }

    // ---- per-cell loss ----
    // layout per cell: [0..4]=box0 cx,cy,w,h,conf  [5..9]=box1  [10..29]=classes
    float iou00 = iou_xywh(p[0], p[1], p[2], p[3], t[0], t[1], t[2], t[3]);
    float iou10 = iou_xywh(p[5], p[6], p[7], p[8], t[0], t[1], t[2], t[3]);
    float iou11 = iou_xywh(p[5], p[6], p[7], p[8], t[5], t[6], t[7], t[8]);

    bool obj = t[4] > 0.0f;          // tgt conf of box0 (== obj mask)
    bool best1 = iou10 > iou00;      // argmax first-max tie-break

    float d0 = p[4] - t[4];  float c0 = d0 * d0;
    float d1 = p[9] - t[9];  float c1 = d1 * d1;
    float conf_best  = best1 ? c1 : c0;
    float conf_other = best1 ? c0 : c1;

    float iou_pair_best = best1 ? iou11 : iou00;
    float coord = 1.0f - sqrtf(fmaxf(iou_pair_best, EPSF));  // ALPHA=0.5

    float cls = 0.0f;
    #pragma unroll
    for (int k = 0; k < 20; ++k) {
        float d = p[10 + k] - t[10 + k];
        cls = fmaf(d, d, cls);
    }

    float loss_obj   = obj ? conf_best : 0.0f;
    float loss_noobj = obj ? conf_other : (c0 + c1);
    float loss_coord = obj ? coord : 0.0f;
    float loss_cls   = obj ? cls : 0.0f;

    float loss = LAMBDA_COORD * loss_coord + loss_obj
               + LAMBDA_NOOBJ * loss_noobj + loss_cls;

    // ---- block reduce ----
    #pragma unroll
    for (int off = 32; off > 0; off >>= 1)
        loss += __shfl_down(loss, off, 64);

    __shared__ float wsum[4];
    int lane = tid & 63;
    int wid  = tid >> 6;
    if (lane == 0) wsum[wid] = loss;
    __syncthreads();
    if (tid == 0)
        partial[blockIdx.x] = wsum[0] + wsum[1] + wsum[2] + wsum[3];
}

__global__ __launch_bounds__(64) void yolo_reduce_kernel(
        const float* __restrict__ partial, int n,
        float* __restrict__ out, float inv_n) {
    // single wave: no barriers at all
    double s = 0.0;
    for (int i = threadIdx.x; i < n; i += 64)
        s += (double)partial[i];
    #pragma unroll
    for (int off = 32; off > 0; off >>= 1)
        s += __shfl_down(s, off, 64);
    if (threadIdx.x == 0)
        out[0] = (float)(s * (double)inv_n);
}

extern "C" void kernel_launch(void* const* d_in, const int* in_sizes, int n_in,
                              void* d_out, int out_size, void* d_ws, size_t ws_size,
                              hipStream_t stream) {
    const float* pred = (const float*)d_in[0];
    const float* tgt  = (const float*)d_in[1];
    float* out = (float*)d_out;

    int total_elems = in_sizes[0];          // N * S * S * 30
    int ncells = total_elems / CELLF;       // N * 196 = 802816 (exact 3136*256)
    int N = ncells / (S_DIM * S_DIM);       // 4096

    int nblocks = ncells / TPB;             // 3136
    float* partial = (float*)d_ws;          // nblocks * 4 B

    yolo_loss_kernel<<<nblocks, TPB, 0, stream>>>(pred, tgt, partial);
    yolo_reduce_kernel<<<1, 64, 0, stream>>>(partial, nblocks, out, 1.0f / (float)N);
}

// Round 10
// 36.087 us; speedup vs baseline: 3.8663x; 1.2473x over previous
//
#include <hip/hip_runtime.h>

// YOLO loss: pred/target (N,14,14,30) fp32 -> scalar.
// S=14, B=2, C=20, cell stride = 30 floats = 120 bytes.
//
// R10 = R5 verbatim (best measured: 37.9 us — two-phase 31 KB register
// staging, fully inlined, 256 threads, ~40% occ) + vectorized reduce
// kernel (float4 loads, fixed-order double accumulation).
// Structure ledger: fusion abandoned (R3/R4 scratch, R7 ACQ_REL L2-nuke,
// R8 cacheline ping-pong); 61 KB single-phase abandoned (R9 occupancy
// cliff); DMA vs register staging is a wash (R5 vs R6).

#define S_DIM 14
#define CELLF 30
#define TPB 256
#define CHUNKF (TPB * CELLF)   // 7680 floats per array per block
#define CHUNK2 (CHUNKF / 2)    // 3840 float2 per array per block

constexpr float LAMBDA_COORD = 5.0f;
constexpr float LAMBDA_NOOBJ = 0.5f;
constexpr float EPSF = 1e-7f;

__device__ __forceinline__ float iou_xywh(float cx1, float cy1, float w1, float h1,
                                          float cx2, float cy2, float w2, float h2) {
    float ix1 = fmaxf(cx1 - 0.5f * w1, cx2 - 0.5f * w2);
    float iy1 = fmaxf(cy1 - 0.5f * h1, cy2 - 0.5f * h2);
    float ix2 = fminf(cx1 + 0.5f * w1, cx2 + 0.5f * w2);
    float iy2 = fminf(cy1 + 0.5f * h1, cy2 + 0.5f * h2);
    float inter = fmaxf(ix2 - ix1, 0.0f) * fmaxf(iy2 - iy1, 0.0f);
    float uni = w1 * h1 + w2 * h2 - inter + EPSF;
    return inter / uni;
}

__global__ __launch_bounds__(TPB, 4) void yolo_loss_kernel(
        const float* __restrict__ pred,
        const float* __restrict__ tgt,
        float* __restrict__ partial) {
    __shared__ float lds[CHUNKF];   // 30720 B

    const int tid = threadIdx.x;
    const size_t base2 = (size_t)blockIdx.x * CHUNK2;   // float2 index into each array
    const float2* pred2 = reinterpret_cast<const float2*>(pred);
    const float2* tgt2  = reinterpret_cast<const float2*>(tgt);
    float2* lds2 = reinterpret_cast<float2*>(lds);

    // ---------------- phase 1: pred -> LDS -> p[30] ----------------
    float2 s[15];
    #pragma unroll
    for (int k = 0; k < 15; ++k)
        s[k] = pred2[base2 + tid + k * TPB];            // coalesced, exact cover
    #pragma unroll
    for (int k = 0; k < 15; ++k)
        lds2[tid + k * TPB] = s[k];                     // linear, conflict-free
    __syncthreads();

    float p[CELLF];
    #pragma unroll
    for (int k = 0; k < 15; ++k) {
        float2 v = lds2[tid * 15 + k];                  // cell gather, 4-way bank
        p[2 * k] = v.x; p[2 * k + 1] = v.y;
    }
    __syncthreads();

    // ---------------- phase 2: tgt -> LDS -> t[30] ----------------
    #pragma unroll
    for (int k = 0; k < 15; ++k)
        s[k] = tgt2[base2 + tid + k * TPB];
    #pragma unroll
    for (int k = 0; k < 15; ++k)
        lds2[tid + k * TPB] = s[k];
    __syncthreads();

    float t[CELLF];
    #pragma unroll
    for (int k = 0; k < 15; ++k) {
        float2 v = lds2[tid * 15 + k];
        t[2 * k] = v.x; t[2 * k + 1] = v.y;
    }

    // ---------------- per-cell loss ----------------
    // layout per cell: [0..4]=box0 cx,cy,w,h,conf  [5..9]=box1  [10..29]=classes
    float iou00 = iou_xywh(p[0], p[1], p[2], p[3], t[0], t[1], t[2], t[3]);
    float iou10 = iou_xywh(p[5], p[6], p[7], p[8], t[0], t[1], t[2], t[3]);
    float iou11 = iou_xywh(p[5], p[6], p[7], p[8], t[5], t[6], t[7], t[8]);

    bool obj = t[4] > 0.0f;          // tgt conf of box0 (== obj mask)
    bool best1 = iou10 > iou00;      // argmax first-max tie-break

    float d0 = p[4] - t[4];  float c0 = d0 * d0;
    float d1 = p[9] - t[9];  float c1 = d1 * d1;
    float conf_best  = best1 ? c1 : c0;
    float conf_other = best1 ? c0 : c1;

    float iou_pair_best = best1 ? iou11 : iou00;
    float coord = 1.0f - sqrtf(fmaxf(iou_pair_best, EPSF));  // ALPHA=0.5

    float cls = 0.0f;
    #pragma unroll
    for (int k = 0; k < 20; ++k) {
        float d = p[10 + k] - t[10 + k];
        cls = fmaf(d, d, cls);
    }

    float loss_obj   = obj ? conf_best : 0.0f;
    float loss_noobj = obj ? conf_other : (c0 + c1);
    float loss_coord = obj ? coord : 0.0f;
    float loss_cls   = obj ? cls : 0.0f;

    float loss = LAMBDA_COORD * loss_coord + loss_obj
               + LAMBDA_NOOBJ * loss_noobj + loss_cls;

    // ---------------- block reduce ----------------
    #pragma unroll
    for (int off = 32; off > 0; off >>= 1)
        loss += __shfl_down(loss, off, 64);

    __shared__ float wsum[4];
    int lane = tid & 63;
    int wid  = tid >> 6;
    if (lane == 0) wsum[wid] = loss;
    __syncthreads();
    if (tid == 0)
        partial[blockIdx.x] = wsum[0] + wsum[1] + wsum[2] + wsum[3];
}

__global__ __launch_bounds__(256) void yolo_reduce_kernel(
        const float* __restrict__ partial, int n4,   // n4 = n/4 float4 groups
        float* __restrict__ out, float inv_n) {
    const float4* p4 = reinterpret_cast<const float4*>(partial);
    double s = 0.0;
    #pragma unroll
    for (int k = 0; k < 4; ++k) {
        int i = threadIdx.x + k * 256;
        if (i < n4) {
            float4 v = p4[i];
            s += (double)v.x; s += (double)v.y;
            s += (double)v.z; s += (double)v.w;
        }
    }
    #pragma unroll
    for (int off = 32; off > 0; off >>= 1)
        s += __shfl_down(s, off, 64);
    __shared__ double wsum[4];
    int lane = threadIdx.x & 63;
    int wid  = threadIdx.x >> 6;
    if (lane == 0) wsum[wid] = s;
    __syncthreads();
    if (threadIdx.x == 0) {
        double tot = wsum[0] + wsum[1] + wsum[2] + wsum[3];
        out[0] = (float)(tot * (double)inv_n);
    }
}

extern "C" void kernel_launch(void* const* d_in, const int* in_sizes, int n_in,
                              void* d_out, int out_size, void* d_ws, size_t ws_size,
                              hipStream_t stream) {
    const float* pred = (const float*)d_in[0];
    const float* tgt  = (const float*)d_in[1];
    float* out = (float*)d_out;

    int total_elems = in_sizes[0];          // N * S * S * 30
    int ncells = total_elems / CELLF;       // N * 196 = 802816 (exact 3136*256)
    int N = ncells / (S_DIM * S_DIM);       // 4096

    int nblocks = ncells / TPB;             // 3136 (divisible by 4)
    float* partial = (float*)d_ws;          // nblocks * 4 B

    yolo_loss_kernel<<<nblocks, TPB, 0, stream>>>(pred, tgt, partial);
    yolo_reduce_kernel<<<1, 256, 0, stream>>>(partial, nblocks / 4, out, 1.0f / (float)N);
}